// Round 5
// baseline (2734.630 us; speedup 1.0000x reference)
//
#include <hip/hip_runtime.h>
#include <hip/hip_bf16.h>
#include <cstdint>
#include <cstddef>

// MHA forward. b=4, n=2048, d_model=1024, heads=16, dk=64, causal.
// Inputs: float32 (empirically confirmed: bf16-reads NaN'd in R1/R2).
// Output: float32 (per contract: reference output dtype; R3/R4 wrote bf16 -> garbage).
// Compute: bf16 MFMA with fp32 accumulate; intermediates bf16.
//
// Pipeline (R5 = R4 localization build + f32 output fix):
//   detect dtype -> flag in ws (safety; f32 path expected)
//   q = Q @ w_q^T -> ws   k = K @ w_k^T -> ws   v = V @ w_v^T -> d_out lower half (bf16)
//   attn (simple per-lane online softmax, causal) -> overwrites q in ws
//   out = attn @ w_o^T -> d_out (float32, overwrites parked v after it is consumed)

typedef __bf16 bf16_t;
typedef bf16_t bf16x8 __attribute__((ext_vector_type(8)));
typedef float floatx4 __attribute__((ext_vector_type(4)));

#define MFMA(a, b, c) __builtin_amdgcn_mfma_f32_16x16x32_bf16((a), (b), (c), 0, 0, 0)
#define NEG_BIG (-30000.0f)  // exp2-domain sentinel; v_exp_f32 underflows to 0

static __device__ __forceinline__ bf16_t f2bf(float x) { return (bf16_t)x; }

static __device__ __forceinline__ bf16x8 cvt8(const float* p) {
  const floatx4 a = *(const floatx4*)p;
  const floatx4 b = *(const floatx4*)(p + 4);
  bf16x8 r;
  r[0] = (bf16_t)a[0]; r[1] = (bf16_t)a[1]; r[2] = (bf16_t)a[2]; r[3] = (bf16_t)a[3];
  r[4] = (bf16_t)b[0]; r[5] = (bf16_t)b[1]; r[6] = (bf16_t)b[2]; r[7] = (bf16_t)b[3];
  return r;
}

// f32-vs-bf16 sniffer on w_q's first 64 uint16s (validated R3: picked f32).
__global__ void detect_dtype(const unsigned short* __restrict__ w,
                             int* __restrict__ flag) {
  const unsigned short u = w[threadIdx.x];
  const bool big = (u & 0x7F80u) >= 0x3F80u;
  const unsigned long long m = __ballot(big);
  if (threadIdx.x == 0) *flag = (m != 0ull) ? 1 : 0;
}

// ---------------------------------------------------------------------------
// C[M,1024] = A[M,1024] @ W[1024,1024]^T, row-major, OutT out (bf16 or f32).
// ADT: 0 = A external (f32/bf16 per flag), 1 = A internal bf16.
// Tile 128x128, BK=32, 4 waves (2x2), 4x4 mfma_16x16x32 per wave.
// LDS stride 40 (16B-aligned rows, <=2-way bank aliasing = free).
// ---------------------------------------------------------------------------
template <int ADT, typename OutT>
__global__ __launch_bounds__(256, 2)
void gemm_bt(const void* __restrict__ Av, const void* __restrict__ Wv,
             OutT* __restrict__ C, const int* __restrict__ flag)
{
  const int K = 1024;
  __shared__ __align__(16) bf16_t sA[128 * 40];
  __shared__ __align__(16) bf16_t sB[128 * 40];
  const int tid  = threadIdx.x;
  const int wave = tid >> 6;
  const int lane = tid & 63;
  const int wm = wave >> 1, wn = wave & 1;
  const int bm = blockIdx.y * 128, bn = blockIdx.x * 128;
  const int quad = lane >> 4, r16 = lane & 15;
  const int f32in = *flag;

  floatx4 acc[4][4];
  #pragma unroll
  for (int i = 0; i < 4; ++i)
    #pragma unroll
    for (int j = 0; j < 4; ++j) acc[i][j] = {0.f, 0.f, 0.f, 0.f};

  const int srow = tid >> 2;       // 0..63
  const int scol = (tid & 3) * 8;  // 0,8,16,24
  const int ar0 = bm + srow, ar1 = bm + srow + 64;
  const int wr0 = bn + srow, wr1 = bn + srow + 64;

  for (int k0 = 0; k0 < K; k0 += 32) {
    bf16x8 va0, va1, vb0, vb1;
    if (ADT == 0 && f32in) {
      const float* Af = (const float*)Av;
      va0 = cvt8(Af + (size_t)ar0 * K + k0 + scol);
      va1 = cvt8(Af + (size_t)ar1 * K + k0 + scol);
    } else {
      const bf16_t* Ab = (const bf16_t*)Av;
      va0 = *(const bf16x8*)(Ab + (size_t)ar0 * K + k0 + scol);
      va1 = *(const bf16x8*)(Ab + (size_t)ar1 * K + k0 + scol);
    }
    if (f32in) {
      const float* Wf = (const float*)Wv;
      vb0 = cvt8(Wf + (size_t)wr0 * K + k0 + scol);
      vb1 = cvt8(Wf + (size_t)wr1 * K + k0 + scol);
    } else {
      const bf16_t* Wb = (const bf16_t*)Wv;
      vb0 = *(const bf16x8*)(Wb + (size_t)wr0 * K + k0 + scol);
      vb1 = *(const bf16x8*)(Wb + (size_t)wr1 * K + k0 + scol);
    }
    *(bf16x8*)&sA[srow * 40 + scol]        = va0;
    *(bf16x8*)&sA[(srow + 64) * 40 + scol] = va1;
    *(bf16x8*)&sB[srow * 40 + scol]        = vb0;
    *(bf16x8*)&sB[(srow + 64) * 40 + scol] = vb1;
    __syncthreads();

    bf16x8 af[4], bv[4];
    #pragma unroll
    for (int mi = 0; mi < 4; ++mi)
      af[mi] = *(const bf16x8*)&sA[(wm * 64 + mi * 16 + r16) * 40 + quad * 8];
    #pragma unroll
    for (int ni = 0; ni < 4; ++ni)
      bv[ni] = *(const bf16x8*)&sB[(wn * 64 + ni * 16 + r16) * 40 + quad * 8];
    #pragma unroll
    for (int mi = 0; mi < 4; ++mi)
      #pragma unroll
      for (int ni = 0; ni < 4; ++ni)
        acc[mi][ni] = MFMA(af[mi], bv[ni], acc[mi][ni]);
    __syncthreads();
  }

  #pragma unroll
  for (int mi = 0; mi < 4; ++mi)
    #pragma unroll
    for (int ni = 0; ni < 4; ++ni)
      #pragma unroll
      for (int r = 0; r < 4; ++r) {
        const int row = bm + wm * 64 + mi * 16 + quad * 4 + r;
        const int col = bn + wn * 64 + ni * 16 + r16;
        C[(size_t)row * 1024 + col] = (OutT)acc[mi][ni][r];
      }
}

// ---------------------------------------------------------------------------
// Simple causal attention, row-major q/k/v [b*n, 1024] bf16, head = 64-col slice.
// Block = 256 threads, one lane = one query row; grid (8 row-chunks, 64 bh).
// K/V tiles (64x64) staged to LDS as f32 (stride 68); per-lane online softmax.
// In-place output over q rows (block-private). Correctness by construction.
// ---------------------------------------------------------------------------
__global__ __launch_bounds__(256)
void attn_simple(bf16_t* qio, const bf16_t* __restrict__ kws,
                 const bf16_t* __restrict__ vws)
{
  __shared__ __align__(16) float Ksh[64 * 68];
  __shared__ __align__(16) float Vsh[64 * 68];
  const int tid = threadIdx.x;
  const int b = blockIdx.y >> 4, h = blockIdx.y & 15;
  const int row = blockIdx.x * 256 + tid;  // n index, 0..2047
  const size_t hb = ((size_t)b * 2048) * 1024 + (size_t)h * 64;

  const float sc = 0.125f * 1.44269504089f;  // 1/sqrt(64) * log2(e)
  float qr[64];
  {
    const bf16_t* qp = qio + hb + (size_t)row * 1024;
    #pragma unroll
    for (int j = 0; j < 8; ++j) {
      const bf16x8 v = *(const bf16x8*)(qp + j * 8);
      #pragma unroll
      for (int e = 0; e < 8; ++e) qr[j * 8 + e] = (float)v[e] * sc;
    }
  }
  float m = NEG_BIG, l = 0.f, o[64];
  #pragma unroll
  for (int d = 0; d < 64; ++d) o[d] = 0.f;

  const int rowmax = blockIdx.x * 256 + 255;
  const int srow = tid >> 2, scol = (tid & 3) * 16;

  for (int kv0 = 0; kv0 <= rowmax; kv0 += 64) {
    {  // stage K,V tile (thread -> 16 elements of one kv row)
      const size_t g = hb + (size_t)(kv0 + srow) * 1024 + scol;
      const bf16x8 ka = *(const bf16x8*)(kws + g), kb = *(const bf16x8*)(kws + g + 8);
      const bf16x8 va = *(const bf16x8*)(vws + g), vb = *(const bf16x8*)(vws + g + 8);
      #pragma unroll
      for (int e = 0; e < 8; ++e) {
        Ksh[srow * 68 + scol + e]     = (float)ka[e];
        Ksh[srow * 68 + scol + 8 + e] = (float)kb[e];
        Vsh[srow * 68 + scol + e]     = (float)va[e];
        Vsh[srow * 68 + scol + 8 + e] = (float)vb[e];
      }
    }
    __syncthreads();

    if (kv0 <= row) {  // wave-uniform (row runs are 64-aligned)
      for (int kvl = 0; kvl < 64; ++kvl) {
        const int kv = kv0 + kvl;
        float s = 0.f;
        #pragma unroll
        for (int d = 0; d < 64; ++d) s += qr[d] * Ksh[kvl * 68 + d];
        s = (kv > row) ? NEG_BIG : s;
        const float mnew  = fmaxf(m, s);
        const float alpha = exp2f(m - mnew);
        const float p     = exp2f(s - mnew);
        l = l * alpha + p;
        #pragma unroll
        for (int d = 0; d < 64; ++d)
          o[d] = o[d] * alpha + p * Vsh[kvl * 68 + d];
        m = mnew;
      }
    }
    __syncthreads();
  }

  const float inv = 1.f / l;
  bf16_t* op = qio + hb + (size_t)row * 1024;
  #pragma unroll
  for (int j = 0; j < 8; ++j) {
    bf16x8 v;
    #pragma unroll
    for (int e = 0; e < 8; ++e) v[e] = f2bf(o[j * 8 + e] * inv);
    *(bf16x8*)(op + j * 8) = v;
  }
}

// ---------------------------------------------------------------------------
extern "C" void kernel_launch(void* const* d_in, const int* in_sizes, int n_in,
                              void* d_out, int out_size, void* d_ws, size_t ws_size,
                              hipStream_t stream) {
  (void)in_sizes; (void)n_in; (void)out_size; (void)ws_size;
  const size_t TSZ = (size_t)8192 * 1024;
  int*    flag = (int*)d_ws;
  bf16_t* qws  = (bf16_t*)((char*)d_ws + 16);
  bf16_t* kws  = qws + TSZ;
  bf16_t* vws  = (bf16_t*)d_out;  // bf16 v parked in f32 out buffer (16.8 of 33.6 MB)

  detect_dtype<<<1, 64, 0, stream>>>((const unsigned short*)d_in[3], flag);

  const dim3 gg(8, 64);  // (N/128, M/128)
  gemm_bt<0, bf16_t><<<gg, 256, 0, stream>>>(d_in[0], d_in[3], qws, flag);
  gemm_bt<0, bf16_t><<<gg, 256, 0, stream>>>(d_in[1], d_in[4], kws, flag);
  gemm_bt<0, bf16_t><<<gg, 256, 0, stream>>>(d_in[2], d_in[5], vws, flag);
  attn_simple<<<dim3(8, 64), 256, 0, stream>>>(qws, kws, vws);
  gemm_bt<1, float><<<gg, 256, 0, stream>>>(qws, d_in[6], (float*)d_out, flag);
}

// Round 6
// 667.613 us; speedup vs baseline: 4.0961x; 4.0961x over previous
//
#include <hip/hip_runtime.h>
#include <hip/hip_bf16.h>
#include <cstdint>
#include <cstddef>

// MHA forward. b=4, n=2048, d_model=1024, heads=16, dk=64, causal.
// Inputs: float32 (confirmed R1-R5). Output: float32 (confirmed R5 green).
// Compute: bf16 MFMA, fp32 accumulate; intermediates bf16 row-major [b*n,1024].
//
// R6: replace the localization-build scalar attention (2563 us, MfmaUtil=0)
// with the R3-validated MFMA flash attention, re-addressed for row-major
// intermediates (head = 64-col slice, row stride 1024). GEMMs untouched.
//
// Pipeline:
//   detect dtype -> flag (safety)
//   q = Q @ w_q^T -> ws   k = K @ w_k^T -> ws   v = V @ w_v^T -> d_out (parked bf16)
//   flash attention (causal, online softmax, MFMA) -> overwrites q in ws
//   out = attn @ w_o^T -> d_out (float32)

typedef __bf16 bf16_t;
typedef bf16_t bf16x8 __attribute__((ext_vector_type(8)));
typedef float floatx4 __attribute__((ext_vector_type(4)));

#define MFMA(a, b, c) __builtin_amdgcn_mfma_f32_16x16x32_bf16((a), (b), (c), 0, 0, 0)
#define NEG_BIG (-30000.0f)  // exp2-domain sentinel; v_exp_f32 underflows to 0

static __device__ __forceinline__ bf16_t f2bf(float x) { return (bf16_t)x; }

static __device__ __forceinline__ bf16x8 cvt8(const float* p) {
  const floatx4 a = *(const floatx4*)p;
  const floatx4 b = *(const floatx4*)(p + 4);
  bf16x8 r;
  r[0] = (bf16_t)a[0]; r[1] = (bf16_t)a[1]; r[2] = (bf16_t)a[2]; r[3] = (bf16_t)a[3];
  r[4] = (bf16_t)b[0]; r[5] = (bf16_t)b[1]; r[6] = (bf16_t)b[2]; r[7] = (bf16_t)b[3];
  return r;
}

// f32-vs-bf16 sniffer on w_q's first 64 uint16s (validated: picks f32 path).
__global__ void detect_dtype(const unsigned short* __restrict__ w,
                             int* __restrict__ flag) {
  const unsigned short u = w[threadIdx.x];
  const bool big = (u & 0x7F80u) >= 0x3F80u;
  const unsigned long long m = __ballot(big);
  if (threadIdx.x == 0) *flag = (m != 0ull) ? 1 : 0;
}

// ---------------------------------------------------------------------------
// C[M,1024] = A[M,1024] @ W[1024,1024]^T, row-major, OutT out (bf16 or f32).
// ADT: 0 = A external (f32/bf16 per flag), 1 = A internal bf16.
// Tile 128x128, BK=32, 4 waves (2x2), 4x4 mfma_16x16x32 per wave.
// LDS stride 40 (16B-aligned rows, <=2-way bank aliasing = free).   [R5 green]
// ---------------------------------------------------------------------------
template <int ADT, typename OutT>
__global__ __launch_bounds__(256, 2)
void gemm_bt(const void* __restrict__ Av, const void* __restrict__ Wv,
             OutT* __restrict__ C, const int* __restrict__ flag)
{
  const int K = 1024;
  __shared__ __align__(16) bf16_t sA[128 * 40];
  __shared__ __align__(16) bf16_t sB[128 * 40];
  const int tid  = threadIdx.x;
  const int wave = tid >> 6;
  const int lane = tid & 63;
  const int wm = wave >> 1, wn = wave & 1;
  const int bm = blockIdx.y * 128, bn = blockIdx.x * 128;
  const int quad = lane >> 4, r16 = lane & 15;
  const int f32in = *flag;

  floatx4 acc[4][4];
  #pragma unroll
  for (int i = 0; i < 4; ++i)
    #pragma unroll
    for (int j = 0; j < 4; ++j) acc[i][j] = {0.f, 0.f, 0.f, 0.f};

  const int srow = tid >> 2;       // 0..63
  const int scol = (tid & 3) * 8;  // 0,8,16,24
  const int ar0 = bm + srow, ar1 = bm + srow + 64;
  const int wr0 = bn + srow, wr1 = bn + srow + 64;

  for (int k0 = 0; k0 < K; k0 += 32) {
    bf16x8 va0, va1, vb0, vb1;
    if (ADT == 0 && f32in) {
      const float* Af = (const float*)Av;
      va0 = cvt8(Af + (size_t)ar0 * K + k0 + scol);
      va1 = cvt8(Af + (size_t)ar1 * K + k0 + scol);
    } else {
      const bf16_t* Ab = (const bf16_t*)Av;
      va0 = *(const bf16x8*)(Ab + (size_t)ar0 * K + k0 + scol);
      va1 = *(const bf16x8*)(Ab + (size_t)ar1 * K + k0 + scol);
    }
    if (f32in) {
      const float* Wf = (const float*)Wv;
      vb0 = cvt8(Wf + (size_t)wr0 * K + k0 + scol);
      vb1 = cvt8(Wf + (size_t)wr1 * K + k0 + scol);
    } else {
      const bf16_t* Wb = (const bf16_t*)Wv;
      vb0 = *(const bf16x8*)(Wb + (size_t)wr0 * K + k0 + scol);
      vb1 = *(const bf16x8*)(Wb + (size_t)wr1 * K + k0 + scol);
    }
    *(bf16x8*)&sA[srow * 40 + scol]        = va0;
    *(bf16x8*)&sA[(srow + 64) * 40 + scol] = va1;
    *(bf16x8*)&sB[srow * 40 + scol]        = vb0;
    *(bf16x8*)&sB[(srow + 64) * 40 + scol] = vb1;
    __syncthreads();

    bf16x8 af[4], bv[4];
    #pragma unroll
    for (int mi = 0; mi < 4; ++mi)
      af[mi] = *(const bf16x8*)&sA[(wm * 64 + mi * 16 + r16) * 40 + quad * 8];
    #pragma unroll
    for (int ni = 0; ni < 4; ++ni)
      bv[ni] = *(const bf16x8*)&sB[(wn * 64 + ni * 16 + r16) * 40 + quad * 8];
    #pragma unroll
    for (int mi = 0; mi < 4; ++mi)
      #pragma unroll
      for (int ni = 0; ni < 4; ++ni)
        acc[mi][ni] = MFMA(af[mi], bv[ni], acc[mi][ni]);
    __syncthreads();
  }

  #pragma unroll
  for (int mi = 0; mi < 4; ++mi)
    #pragma unroll
    for (int ni = 0; ni < 4; ++ni)
      #pragma unroll
      for (int r = 0; r < 4; ++r) {
        const int row = bm + wm * 64 + mi * 16 + quad * 4 + r;
        const int col = bn + wn * 64 + ni * 16 + r16;
        C[(size_t)row * 1024 + col] = (OutT)acc[mi][ni][r];
      }
}

// ---------------------------------------------------------------------------
// Causal MFMA flash attention over row-major [8192][1024] bf16 q/k/v, head =
// 64-col slice. Block = 256 threads (4 waves): one (bh, 128-row q-tile).
// Wave w owns S/O rows [w*32, w*32+32). BKV = 64. Finite mask sentinels.
// P round-trips through LDS (C-layout -> A-operand layout, m120 transform).
// V staged transposed (sVt[d][kv], stride 72 -> 2-way bank aliasing = free).
// Output in-place over q rows (block-private). Validated: R3==R4 bit-identical.
// ---------------------------------------------------------------------------
__global__ __launch_bounds__(256, 2)
void flash_attn(bf16_t* qio, const bf16_t* __restrict__ kh,
                const bf16_t* __restrict__ vh)
{
  __shared__ __align__(16) bf16_t sK[64 * 72];    // [kv][d]  9 KB
  __shared__ __align__(16) bf16_t sVt[64 * 72];   // [d][kv]  9 KB
  __shared__ __align__(16) bf16_t sP[128 * 72];   // [q][kv] 18 KB
  const int tid  = threadIdx.x;
  const int wave = tid >> 6;
  const int lane = tid & 63;
  const int quad = lane >> 4, r16 = lane & 15;
  const int b = blockIdx.y >> 4, h = blockIdx.y & 15;
  const int q0 = (gridDim.x - 1 - blockIdx.x) * 128;  // heavy tiles first
  const size_t hb = ((size_t)b * 2048) * 1024 + (size_t)h * 64;

  // Q fragments (reused across all kv tiles): rows wave*32 + mi*16 + r16
  bf16x8 qf[2][2];
  #pragma unroll
  for (int mi = 0; mi < 2; ++mi)
    #pragma unroll
    for (int ks = 0; ks < 2; ++ks)
      qf[mi][ks] = *(const bf16x8*)(qio + hb +
          (size_t)(q0 + wave * 32 + mi * 16 + r16) * 1024 + ks * 32 + quad * 8);

  floatx4 o[2][4];
  float mrow[2][4], lrow[2][4];
  #pragma unroll
  for (int mi = 0; mi < 2; ++mi) {
    #pragma unroll
    for (int nd = 0; nd < 4; ++nd) o[mi][nd] = {0.f, 0.f, 0.f, 0.f};
    #pragma unroll
    for (int r = 0; r < 4; ++r) { mrow[mi][r] = NEG_BIG; lrow[mi][r] = 0.f; }
  }

  const float sc = 0.125f * 1.44269504089f;  // 1/sqrt(64) * log2(e)
  const int kend = q0 + 128;

  for (int kv0 = 0; kv0 < kend; kv0 += 64) {
    // ---- stage K tile (row-major, padded) and V tile (transposed) ----
    #pragma unroll
    for (int j = 0; j < 2; ++j) {
      const int c = j * 256 + tid;
      const int krow = c >> 3, kcol = (c & 7) * 8;
      *(bf16x8*)&sK[krow * 72 + kcol] =
          *(const bf16x8*)(kh + hb + (size_t)(kv0 + krow) * 1024 + kcol);
      const int vkv = c & 63, vd = (c >> 6) * 8;
      const bf16x8 vv = *(const bf16x8*)(vh + hb + (size_t)(kv0 + vkv) * 1024 + vd);
      #pragma unroll
      for (int e = 0; e < 8; ++e) sVt[(vd + e) * 72 + vkv] = vv[e];
    }
    __syncthreads();

    // ---- S = Q K^T ----
    floatx4 s[2][4];
    #pragma unroll
    for (int mi = 0; mi < 2; ++mi)
      #pragma unroll
      for (int nk = 0; nk < 4; ++nk) s[mi][nk] = {0.f, 0.f, 0.f, 0.f};
    #pragma unroll
    for (int ks = 0; ks < 2; ++ks) {
      bf16x8 bk[4];
      #pragma unroll
      for (int nk = 0; nk < 4; ++nk)
        bk[nk] = *(const bf16x8*)&sK[(nk * 16 + r16) * 72 + ks * 32 + quad * 8];
      #pragma unroll
      for (int mi = 0; mi < 2; ++mi)
        #pragma unroll
        for (int nk = 0; nk < 4; ++nk)
          s[mi][nk] = MFMA(qf[mi][ks], bk[nk], s[mi][nk]);
    }

    // ---- scale + causal mask (exp2 domain, finite sentinel) ----
    const bool domask = (kv0 + 63 > q0);
    #pragma unroll
    for (int mi = 0; mi < 2; ++mi) {
      const int rowb = q0 + wave * 32 + mi * 16 + quad * 4;
      #pragma unroll
      for (int nk = 0; nk < 4; ++nk) {
        const int col = kv0 + nk * 16 + r16;
        #pragma unroll
        for (int r = 0; r < 4; ++r) {
          float t = s[mi][nk][r] * sc;
          if (domask && col > rowb + r) t = NEG_BIG;
          s[mi][nk][r] = t;
        }
      }
    }

    // ---- online softmax; P -> LDS in A-operand layout ----
    #pragma unroll
    for (int mi = 0; mi < 2; ++mi)
      #pragma unroll
      for (int r = 0; r < 4; ++r) {
        float mx = fmaxf(fmaxf(s[mi][0][r], s[mi][1][r]),
                         fmaxf(s[mi][2][r], s[mi][3][r]));
        #pragma unroll
        for (int off = 8; off >= 1; off >>= 1)
          mx = fmaxf(mx, __shfl_xor(mx, off, 64));
        const float mnew  = fmaxf(mrow[mi][r], mx);
        const float alpha = exp2f(mrow[mi][r] - mnew);
        mrow[mi][r] = mnew;
        float ls = 0.f;
        const int prow = wave * 32 + mi * 16 + quad * 4 + r;
        #pragma unroll
        for (int nk = 0; nk < 4; ++nk) {
          const bf16_t pb = f2bf(exp2f(s[mi][nk][r] - mnew));
          ls += (float)pb;  // denominator matches the bf16 P used in PV
          sP[prow * 72 + nk * 16 + r16] = pb;
        }
        #pragma unroll
        for (int off = 8; off >= 1; off >>= 1)
          ls += __shfl_xor(ls, off, 64);
        lrow[mi][r] = lrow[mi][r] * alpha + ls;
        #pragma unroll
        for (int nd = 0; nd < 4; ++nd) o[mi][nd][r] *= alpha;
      }
    __syncthreads();  // sP visible across lanes

    // ---- O += P V ----
    #pragma unroll
    for (int ks = 0; ks < 2; ++ks) {
      bf16x8 pa[2], vb[4];
      #pragma unroll
      for (int mi = 0; mi < 2; ++mi)
        pa[mi] = *(const bf16x8*)&sP[(wave * 32 + mi * 16 + r16) * 72 + ks * 32 + quad * 8];
      #pragma unroll
      for (int nd = 0; nd < 4; ++nd)
        vb[nd] = *(const bf16x8*)&sVt[(nd * 16 + r16) * 72 + ks * 32 + quad * 8];
      #pragma unroll
      for (int mi = 0; mi < 2; ++mi)
        #pragma unroll
        for (int nd = 0; nd < 4; ++nd)
          o[mi][nd] = MFMA(pa[mi], vb[nd], o[mi][nd]);
    }
    __syncthreads();  // protect sK/sVt/sP for next iteration
  }

  // ---- normalize + store (in-place over q rows; block-private) ----
  #pragma unroll
  for (int mi = 0; mi < 2; ++mi)
    #pragma unroll
    for (int r = 0; r < 4; ++r) {
      const float inv = 1.f / lrow[mi][r];
      const int row = q0 + wave * 32 + mi * 16 + quad * 4 + r;
      #pragma unroll
      for (int nd = 0; nd < 4; ++nd)
        qio[hb + (size_t)row * 1024 + nd * 16 + r16] = f2bf(o[mi][nd][r] * inv);
    }
}

// ---------------------------------------------------------------------------
extern "C" void kernel_launch(void* const* d_in, const int* in_sizes, int n_in,
                              void* d_out, int out_size, void* d_ws, size_t ws_size,
                              hipStream_t stream) {
  (void)in_sizes; (void)n_in; (void)out_size; (void)ws_size;
  const size_t TSZ = (size_t)8192 * 1024;
  int*    flag = (int*)d_ws;
  bf16_t* qws  = (bf16_t*)((char*)d_ws + 16);
  bf16_t* kws  = qws + TSZ;
  bf16_t* vws  = (bf16_t*)d_out;  // bf16 v parked in f32 out buffer

  detect_dtype<<<1, 64, 0, stream>>>((const unsigned short*)d_in[3], flag);

  const dim3 gg(8, 64);  // (N/128, M/128)
  gemm_bt<0, bf16_t><<<gg, 256, 0, stream>>>(d_in[0], d_in[3], qws, flag);
  gemm_bt<0, bf16_t><<<gg, 256, 0, stream>>>(d_in[1], d_in[4], kws, flag);
  gemm_bt<0, bf16_t><<<gg, 256, 0, stream>>>(d_in[2], d_in[5], vws, flag);
  flash_attn<<<dim3(16, 64), 256, 0, stream>>>(qws, kws, vws);
  gemm_bt<1, float><<<gg, 256, 0, stream>>>(qws, d_in[6], (float*)d_out, flag);
}